// Round 18
// baseline (219.644 us; speedup 1.0000x reference)
//
#include <hip/hip_runtime.h>
#include <hip/hip_bf16.h>

typedef __attribute__((ext_vector_type(8))) short bf16x8;
typedef __attribute__((ext_vector_type(4))) float f32x4;
typedef unsigned short u16;

union F8 { bf16x8 v; unsigned u[4]; u16 s[8]; uint4 q; };

__device__ __forceinline__ unsigned pk2(float a, float b) {
    __hip_bfloat162 t = __float22bfloat162_rn(make_float2(a, b));
    unsigned r; __builtin_memcpy(&r, &t, 4); return r;
}
__device__ __forceinline__ u16 f2bf(float a) {
    __hip_bfloat16 t = __float2bfloat16(a);
    u16 r; __builtin_memcpy(&r, &t, 2); return r;
}
__device__ __forceinline__ float bf2f(u16 s) {
    unsigned u = ((unsigned)s) << 16; float f; __builtin_memcpy(&f, &u, 4); return f;
}
#define SWZ(byteoff, row) ((byteoff) ^ (((row) & 7) << 4))
#define MFMA(a, b, c) __builtin_amdgcn_mfma_f32_16x16x32_bf16((a), (b), (c), 0, 0, 0)

// workspace layout (f32-element offsets; ~112 MB total):
//  num1 (4,4096,512) @ 0          num2 (4,2048,512) @ 8388608
//  num4 (4,1024,512) @ 12582912   num8 (4,512,512)  @ 14680064
//  wsum1 (4,4096,8) @ 15728640    wsum2 @ 15859712
//  wsum4 @ 15925248               wsum8 @ 15958016
//  Kb (bf16) @ byte 63897600      Vt (bf16) @ byte 80674816
#define NOFF2 8388608
#define NOFF4 12582912
#define NOFF8 14680064
#define WOFF1 15728640
#define WOFF2 15859712
#define WOFF4 15925248
#define WOFF8 15958016

// ---------------------------------------------------------------------------
// Pre-pass: Kb = bf16(K) same layout; Vt[d] = bf16(V) transposed per dilation:
// Vt[d][bh][dim][jd] = V[bh][jd*d][dim].
// ---------------------------------------------------------------------------
__global__ __launch_bounds__(256)
void prep_kernel(const float* __restrict__ K, const float* __restrict__ V,
                 u16* __restrict__ Kb, u16* __restrict__ Vt)
{
    __shared__ __align__(16) char tl[64 * 128];   // [64 key][64 dim] bf16, swizzled
    int blk = blockIdx.x;
    const int t = threadIdx.x;

    if (blk < 2048) {                              // ---- K convert ----
        const int bh = blk >> 6, qt = blk & 63;
        const int q = qt * 64 + (t >> 2), dd0 = (t & 3) * 16;
        const float* kp = K + ((size_t)bh * 4096 + q) * 64 + dd0;
        float4 x0 = ((const float4*)kp)[0], x1 = ((const float4*)kp)[1];
        float4 x2 = ((const float4*)kp)[2], x3 = ((const float4*)kp)[3];
        F8 f0, f1;
        f0.u[0] = pk2(x0.x, x0.y); f0.u[1] = pk2(x0.z, x0.w);
        f0.u[2] = pk2(x1.x, x1.y); f0.u[3] = pk2(x1.z, x1.w);
        f1.u[0] = pk2(x2.x, x2.y); f1.u[1] = pk2(x2.z, x2.w);
        f1.u[2] = pk2(x3.x, x3.y); f1.u[3] = pk2(x3.z, x3.w);
        u16* op = Kb + ((size_t)bh * 4096 + q) * 64 + dd0;
        ((uint4*)op)[0] = f0.q; ((uint4*)op)[1] = f1.q;
        return;
    }
    blk -= 2048;                                   // ---- V transpose ----
    int d, Ld; size_t vtoff;
    if (blk < 2048)      { d = 1; Ld = 4096; vtoff = 0; }
    else if (blk < 3072) { blk -= 2048; d = 2; Ld = 2048; vtoff = 8388608; }
    else if (blk < 3584) { blk -= 3072; d = 4; Ld = 1024; vtoff = 12582912; }
    else                 { blk -= 3584; d = 8; Ld = 512;  vtoff = 14680064; }
    const int tpb = Ld >> 6;
    const int bh = blk / tpb, jt = blk % tpb;
    {   // load 64 (dilated) rows x 64 dims, cvt, swizzled LDS
        const int j = t >> 2, dd0 = (t & 3) * 16;
        const int q = (jt * 64 + j) * d;
        const float* vp = V + ((size_t)bh * 4096 + q) * 64 + dd0;
        float4 x0 = ((const float4*)vp)[0], x1 = ((const float4*)vp)[1];
        float4 x2 = ((const float4*)vp)[2], x3 = ((const float4*)vp)[3];
        F8 f0, f1;
        f0.u[0] = pk2(x0.x, x0.y); f0.u[1] = pk2(x0.z, x0.w);
        f0.u[2] = pk2(x1.x, x1.y); f0.u[3] = pk2(x1.z, x1.w);
        f1.u[0] = pk2(x2.x, x2.y); f1.u[1] = pk2(x2.z, x2.w);
        f1.u[2] = pk2(x3.x, x3.y); f1.u[3] = pk2(x3.z, x3.w);
        *(uint4*)(tl + SWZ(j * 128 + dd0 * 2, j)) = f0.q;
        *(uint4*)(tl + SWZ(j * 128 + dd0 * 2 + 16, j)) = f1.q;
    }
    __syncthreads();
    {   // store transposed: row = dim, 16 keys per thread
        const int dd = t >> 2, jb = (t & 3) * 16;
        F8 f0, f1;
#pragma unroll
        for (int i = 0; i < 8; ++i) {
            f0.s[i] = *(const u16*)(tl + SWZ((jb + i) * 128 + dd * 2, jb + i));
            f1.s[i] = *(const u16*)(tl + SWZ((jb + 8 + i) * 128 + dd * 2, jb + 8 + i));
        }
        u16* op = Vt + vtoff + ((size_t)bh * 64 + dd) * Ld + jt * 64 + jb;
        ((uint4*)op)[0] = f0.q; ((uint4*)op)[1] = f1.q;
    }
}

// ---------------------------------------------------------------------------
// Fused flash attention — round-13/17 structure (fastest measured). All
// dilations in ONE 1920-block launch; each dilation writes its PRIVATE
// num/wsum slice with plain stores (no atomics, no memset). Round-6 inner
// loop: 256 thr = 4 waves, 32 q-rows/wave, swapped QK^T, no online max (ref
// computes unmaxed exp; scores ~N(0,1)), P via LDS, 1-deep prefetch.
// NEW (r18): row-sum l computed by MFMA against a ones-vector — removes 32
// VALU adds + serial rs chain per tile and the epilogue shfl reduce; the
// 4 extra MFMAs/tile ride the 20%-utilized MFMA pipe.
// ---------------------------------------------------------------------------
__global__ __launch_bounds__(256)
void attn_fused(const float* __restrict__ Q, const u16* __restrict__ Kb,
                const u16* __restrict__ Vt, float* __restrict__ ws)
{
    const int L = 4096;
    const int per = gridDim.x >> 3;                // bijective XCD swizzle
    const int wg0 = blockIdx.x;
    const int wg = (wg0 & 7) * per + (wg0 >> 3);

    int d, npb, bs, rel; size_t vtoff, noff, woff;
    if (wg < 1024)      { d = 1; npb = 32; bs = 1024; rel = wg;
                          vtoff = 0;        noff = 0;     woff = WOFF1; }
    else if (wg < 1536) { d = 2; npb = 16; bs = 1024; rel = wg - 1024;
                          vtoff = 8388608;  noff = NOFF2; woff = WOFF2; }
    else if (wg < 1792) { d = 4; npb = 8;  bs = 1024; rel = wg - 1536;
                          vtoff = 12582912; noff = NOFF4; woff = WOFF4; }
    else                { d = 8; npb = 4;  bs = 512;  rel = wg - 1792;
                          vtoff = 14680064; noff = NOFF8; woff = WOFF8; }

    const int bh = rel / npb;
    const int qt = rel % npb;
    const int b = bh >> 3, h = bh & 7;
    const int tid = threadIdx.x;
    const int w = tid >> 6, lane = tid & 63;
    const int g = lane >> 4, c = lane & 15;
    const int bstart = ((qt * 128) / bs) * bs;
    const int qrow0 = qt * 128 + w * 32;
    const int Ldq = npb * 128;
    const int nt = bs >> 6;

    __shared__ __align__(16) char smem[32 * 1024];
    char* const Kls = smem;
    char* const Vls = smem + 8192;
    char* const Pls = smem + 16384 + w * 4096;

    const size_t base = (size_t)bh * L * 64;
    const size_t vbase = vtoff + (size_t)bh * 64 * Ldq;
    const float qs = 0.125f * 1.44269504088896341f;

    bf16x8 qf[2][2];
#pragma unroll
    for (int qi = 0; qi < 2; ++qi) {
        const float* qp = Q + base + (size_t)(qrow0 + qi * 16 + c) * d * 64 + g * 8;
#pragma unroll
        for (int s2 = 0; s2 < 2; ++s2) {
            float4 x = ((const float4*)(qp + s2 * 32))[0];
            float4 y = ((const float4*)(qp + s2 * 32))[1];
            F8 f;
            f.u[0] = pk2(x.x * qs, x.y * qs);
            f.u[1] = pk2(x.z * qs, x.w * qs);
            f.u[2] = pk2(y.x * qs, y.y * qs);
            f.u[3] = pk2(y.z * qs, y.w * qs);
            qf[qi][s2] = f.v;
        }
    }

    f32x4 o[2][4];
#pragma unroll
    for (int qi = 0; qi < 2; ++qi)
#pragma unroll
        for (int dj = 0; dj < 4; ++dj) o[qi][dj] = (f32x4){0.f, 0.f, 0.f, 0.f};
    f32x4 accl[2];
    accl[0] = (f32x4){0.f, 0.f, 0.f, 0.f};
    accl[1] = (f32x4){0.f, 0.f, 0.f, 0.f};

    F8 ones;
#pragma unroll
    for (int i = 0; i < 4; ++i) ones.u[i] = 0x3F803F80u;   // bf16 1.0 x2

    const int krow = tid >> 2, kc = tid & 3;

    uint4 ka, kb2, va, vb;
    const u16* kp0 = Kb + base + (size_t)(bstart + krow) * d * 64 + kc * 16;
    const u16* vp0 = Vt + vbase + (size_t)lane * Ldq + bstart + w * 16;
    const size_t kstep = (size_t)64 * d * 64;
    ka = ((const uint4*)kp0)[0]; kb2 = ((const uint4*)kp0)[1];
    va = ((const uint4*)vp0)[0]; vb = ((const uint4*)vp0)[1];

    for (int t = 0; t < nt; ++t) {
        *(uint4*)(Kls + SWZ(krow * 128 + kc * 32, krow)) = ka;
        *(uint4*)(Kls + SWZ(krow * 128 + kc * 32 + 16, krow)) = kb2;
        *(uint4*)(Vls + SWZ(lane * 128 + w * 32, lane)) = va;
        *(uint4*)(Vls + SWZ(lane * 128 + w * 32 + 16, lane)) = vb;
        __syncthreads();

        if (t + 1 < nt) {
            const u16* kp = kp0 + (size_t)(t + 1) * kstep;
            const u16* vp = vp0 + (t + 1) * 64;
            ka = ((const uint4*)kp)[0]; kb2 = ((const uint4*)kp)[1];
            va = ((const uint4*)vp)[0]; vb = ((const uint4*)vp)[1];
        }

        f32x4 st[2][4];
#pragma unroll
        for (int kj = 0; kj < 4; ++kj) {
            const int row = 16 * kj + c;
            bf16x8 kf0 = *(const bf16x8*)(Kls + SWZ(row * 128 + g * 16, row));
            bf16x8 kf1 = *(const bf16x8*)(Kls + SWZ(row * 128 + 64 + g * 16, row));
            f32x4 z = (f32x4){0.f, 0.f, 0.f, 0.f};
            st[0][kj] = MFMA(kf1, qf[0][1], MFMA(kf0, qf[0][0], z));
            st[1][kj] = MFMA(kf1, qf[1][1], MFMA(kf0, qf[1][0], z));
        }

#pragma unroll
        for (int qi = 0; qi < 2; ++qi) {
            const int prow = 16 * qi + c;
#pragma unroll
            for (int kj = 0; kj < 4; ++kj) {
                const float p0 = exp2f(st[qi][kj][0]);
                const float p1 = exp2f(st[qi][kj][1]);
                const float p2 = exp2f(st[qi][kj][2]);
                const float p3 = exp2f(st[qi][kj][3]);
                uint2 pv; pv.x = pk2(p0, p1); pv.y = pk2(p2, p3);
                *(uint2*)(Pls + SWZ(prow * 128 + kj * 32 + g * 8, prow)) = pv;
            }
        }

#pragma unroll
        for (int s = 0; s < 2; ++s) {
            bf16x8 vf[4], pf[2];
#pragma unroll
            for (int dj = 0; dj < 4; ++dj) {
                const int row = 16 * dj + c;
                vf[dj] = *(const bf16x8*)(Vls + SWZ(row * 128 + s * 64 + g * 16, row));
            }
#pragma unroll
            for (int qi = 0; qi < 2; ++qi) {
                const int row = 16 * qi + c;
                pf[qi] = *(const bf16x8*)(Pls + SWZ(row * 128 + s * 64 + g * 16, row));
            }
#pragma unroll
            for (int qi = 0; qi < 2; ++qi) {
#pragma unroll
                for (int dj = 0; dj < 4; ++dj)
                    o[qi][dj] = MFMA(pf[qi], vf[dj], o[qi][dj]);
                accl[qi] = MFMA(pf[qi], ones.v, accl[qi]);   // row-sum via MFMA
            }
        }
        __syncthreads();
    }

    // ---- epilogue: plain stores into this dilation's private slice.
    // accl[qi][r] = sum_k P[q=16qi+4g+r][k], replicated across c.
#pragma unroll
    for (int qi = 0; qi < 2; ++qi) {
#pragma unroll
        for (int r = 0; r < 4; ++r) {
            const int q = qrow0 + 16 * qi + 4 * g + r;
            float* np = ws + noff + ((size_t)b * Ldq + q) * 512 + h * 64 + c;
#pragma unroll
            for (int dj = 0; dj < 4; ++dj) np[dj * 16] = o[qi][dj][r];
        }
        if (c == 0) {
#pragma unroll
            for (int r = 0; r < 4; ++r) {
                const int q = qrow0 + 16 * qi + 4 * g + r;
                ws[woff + ((size_t)b * Ldq + q) * 8 + h] = accl[qi][r];
            }
        }
    }
}

// ---------------------------------------------------------------------------
// Merge: fold num2/4/8 (and wsum2/4/8) into slice 1. Row-owned: each even
// row li=2j handled by one 128-lane half-block; branches (li%4, li%8) are
// uniform per half-block -> no divergence penalty, no races, no atomics.
// ---------------------------------------------------------------------------
__global__ __launch_bounds__(256)
void merge_kernel(float* __restrict__ ws)
{
    const int tid = threadIdx.x;
    const int er = blockIdx.x * 2 + (tid >> 7);    // even-row index 0..8191
    const int lane = tid & 127;
    const int b = er >> 11;                        // batch
    const int j = er & 2047;                       // li = 2j
    const int li = 2 * j;

    float4* dst = (float4*)(ws + ((size_t)b * 4096 + li) * 512) + lane;
    float4 a = *dst;
    const float4 x2 = *((const float4*)(ws + NOFF2 + ((size_t)b * 2048 + j) * 512) + lane);
    a.x += x2.x; a.y += x2.y; a.z += x2.z; a.w += x2.w;
    if ((li & 3) == 0) {
        const float4 x4 = *((const float4*)(ws + NOFF4 + ((size_t)b * 1024 + (li >> 2)) * 512) + lane);
        a.x += x4.x; a.y += x4.y; a.z += x4.z; a.w += x4.w;
    }
    if ((li & 7) == 0) {
        const float4 x8 = *((const float4*)(ws + NOFF8 + ((size_t)b * 512 + (li >> 3)) * 512) + lane);
        a.x += x8.x; a.y += x8.y; a.z += x8.z; a.w += x8.w;
    }
    *dst = a;

    if (lane < 8) {
        const int h = lane;
        float add = ws[WOFF2 + ((size_t)b * 2048 + j) * 8 + h];
        if ((li & 3) == 0) add += ws[WOFF4 + ((size_t)b * 1024 + (li >> 2)) * 8 + h];
        if ((li & 7) == 0) add += ws[WOFF8 + ((size_t)b * 512 + (li >> 3)) * 8 + h];
        ws[WOFF1 + ((size_t)b * 4096 + li) * 8 + h] += add;
    }
}

// ---------------------------------------------------------------------------
// out(16384,512) = [num/wsum] @ Wo^T + bo.  128x128 tile, BK=64, 4 waves.
// Split-precision bf16 (hi+lo): 3 MFMAs per product. XCD swizzle for A reuse.
// ---------------------------------------------------------------------------
__global__ __launch_bounds__(256)
void proj_mfma(const float* __restrict__ num, const float* __restrict__ wsum,
               const float* __restrict__ Wo, const float* __restrict__ bo,
               float* __restrict__ out)
{
    __shared__ __align__(16) char smem[64 * 1024];
    char* const Ah = smem;
    char* const Al = smem + 16384;
    char* const Bh = smem + 32768;
    char* const Bl = smem + 49152;

    const int tid = threadIdx.x;
    const int w = tid >> 6, lane = tid & 63, g = lane >> 4, c = lane & 15;
    const int wm = (w >> 1) * 64, wn = (w & 1) * 64;
    const int per = gridDim.x >> 3;
    const int wg0 = blockIdx.x;
    const int wg = (wg0 & 7) * per + (wg0 >> 3);
    const int bm = (wg >> 2) * 128, bn = (wg & 3) * 128;
    const int srow = tid >> 1, koff = (tid & 1) * 32;

    f32x4 acc[4][4];
#pragma unroll
    for (int mi = 0; mi < 4; ++mi)
#pragma unroll
        for (int ni = 0; ni < 4; ++ni) acc[mi][ni] = (f32x4){0.f, 0.f, 0.f, 0.f};

    for (int bk = 0; bk < 512; bk += 64) {
        {
            const float* ap = num + (size_t)(bm + srow) * 512 + bk + koff;
            const float winv = 1.0f / wsum[(size_t)(bm + srow) * 8 + (bk >> 6)];
#pragma unroll
            for (int i = 0; i < 8; ++i) {
                float4 a4 = ((const float4*)ap)[i];
                float v0 = a4.x * winv, v1 = a4.y * winv, v2 = a4.z * winv, v3 = a4.w * winv;
                u16 h0 = f2bf(v0), h1 = f2bf(v1), h2 = f2bf(v2), h3 = f2bf(v3);
                uint2 hiw; hiw.x = h0 | ((unsigned)h1 << 16); hiw.y = h2 | ((unsigned)h3 << 16);
                uint2 lo;
                lo.x = f2bf(v0 - bf2f(h0)) | ((unsigned)f2bf(v1 - bf2f(h1)) << 16);
                lo.y = f2bf(v2 - bf2f(h2)) | ((unsigned)f2bf(v3 - bf2f(h3)) << 16);
                const int off = SWZ(srow * 128 + koff * 2 + i * 8, srow);
                *(uint2*)(Ah + off) = hiw;
                *(uint2*)(Al + off) = lo;
            }
            const float* bp = Wo + (size_t)(bn + srow) * 512 + bk + koff;
#pragma unroll
            for (int i = 0; i < 8; ++i) {
                float4 a4 = ((const float4*)bp)[i];
                u16 h0 = f2bf(a4.x), h1 = f2bf(a4.y), h2 = f2bf(a4.z), h3 = f2bf(a4.w);
                uint2 hiw; hiw.x = h0 | ((unsigned)h1 << 16); hiw.y = h2 | ((unsigned)h3 << 16);
                uint2 lo;
                lo.x = f2bf(a4.x - bf2f(h0)) | ((unsigned)f2bf(a4.y - bf2f(h1)) << 16);
                lo.y = f2bf(a4.z - bf2f(h2)) | ((unsigned)f2bf(a4.w - bf2f(h3)) << 16);
                const int off = SWZ(srow * 128 + koff * 2 + i * 8, srow);
                *(uint2*)(Bh + off) = hiw;
                *(uint2*)(Bl + off) = lo;
            }
        }
        __syncthreads();
#pragma unroll
        for (int s = 0; s < 2; ++s) {
            bf16x8 ah[4], al[4], bh[4], bl[4];
#pragma unroll
            for (int mi = 0; mi < 4; ++mi) {
                const int row = wm + 16 * mi + c;
                const int off = SWZ(row * 128 + s * 64 + g * 16, row);
                ah[mi] = *(const bf16x8*)(Ah + off);
                al[mi] = *(const bf16x8*)(Al + off);
            }
#pragma unroll
            for (int ni = 0; ni < 4; ++ni) {
                const int row = wn + 16 * ni + c;
                const int off = SWZ(row * 128 + s * 64 + g * 16, row);
                bh[ni] = *(const bf16x8*)(Bh + off);
                bl[ni] = *(const bf16x8*)(Bl + off);
            }
#pragma unroll
            for (int mi = 0; mi < 4; ++mi)
#pragma unroll
                for (int ni = 0; ni < 4; ++ni) {
                    acc[mi][ni] = MFMA(ah[mi], bh[ni], acc[mi][ni]);
                    acc[mi][ni] = MFMA(ah[mi], bl[ni], acc[mi][ni]);
                    acc[mi][ni] = MFMA(al[mi], bh[ni], acc[mi][ni]);
                }
        }
        __syncthreads();
    }

    float bias[4];
#pragma unroll
    for (int ni = 0; ni < 4; ++ni) bias[ni] = bo[bn + wn + 16 * ni + c];
#pragma unroll
    for (int mi = 0; mi < 4; ++mi)
#pragma unroll
        for (int r = 0; r < 4; ++r) {
            float* op = out + (size_t)(bm + wm + 16 * mi + 4 * g + r) * 512 + bn + wn + c;
#pragma unroll
            for (int ni = 0; ni < 4; ++ni)
                op[ni * 16] = acc[mi][ni][r] + bias[ni];
        }
}

extern "C" void kernel_launch(void* const* d_in, const int* in_sizes, int n_in,
                              void* d_out, int out_size, void* d_ws, size_t ws_size,
                              hipStream_t stream)
{
    const float* Q  = (const float*)d_in[0];
    const float* K  = (const float*)d_in[1];
    const float* V  = (const float*)d_in[2];
    const float* Wo = (const float*)d_in[3];
    const float* bo = (const float*)d_in[4];
    float* out = (float*)d_out;

    float* ws = (float*)d_ws;
    u16* Kb = (u16*)((char*)d_ws + 63897600);     // 16.78 MB
    u16* Vt = (u16*)((char*)d_ws + 80674816);     // 31.46 MB (ends ~112.1 MB)

    hipLaunchKernelGGL(prep_kernel, dim3(5888), dim3(256), 0, stream, K, V, Kb, Vt);
    hipLaunchKernelGGL(attn_fused, dim3(1920), dim3(256), 0, stream, Q, Kb, Vt, ws);
    hipLaunchKernelGGL(merge_kernel, dim3(4096), dim3(256), 0, stream, ws);
    hipLaunchKernelGGL(proj_mfma, dim3(512), dim3(256), 0, stream,
                       ws, ws + WOFF1, Wo, bo, out);
}

// Round 19
// 194.936 us; speedup vs baseline: 1.1268x; 1.1268x over previous
//
#include <hip/hip_runtime.h>
#include <hip/hip_bf16.h>

typedef __attribute__((ext_vector_type(8))) short bf16x8;
typedef __attribute__((ext_vector_type(4))) float f32x4;
typedef unsigned short u16;

union F8 { bf16x8 v; unsigned u[4]; u16 s[8]; uint4 q; };

__device__ __forceinline__ unsigned pk2(float a, float b) {
    __hip_bfloat162 t = __float22bfloat162_rn(make_float2(a, b));
    unsigned r; __builtin_memcpy(&r, &t, 4); return r;
}
__device__ __forceinline__ u16 f2bf(float a) {
    __hip_bfloat16 t = __float2bfloat16(a);
    u16 r; __builtin_memcpy(&r, &t, 2); return r;
}
__device__ __forceinline__ float bf2f(u16 s) {
    unsigned u = ((unsigned)s) << 16; float f; __builtin_memcpy(&f, &u, 4); return f;
}
#define SWZ(byteoff, row) ((byteoff) ^ (((row) & 7) << 4))
#define MFMA(a, b, c) __builtin_amdgcn_mfma_f32_16x16x32_bf16((a), (b), (c), 0, 0, 0)

// workspace layout (f32-element offsets; ~112 MB total):
//  num1 (4,4096,512) @ 0          num2 (4,2048,512) @ 8388608
//  num4 (4,1024,512) @ 12582912   num8 (4,512,512)  @ 14680064
//  wsum1 (4,4096,8) @ 15728640    wsum2 @ 15859712
//  wsum4 @ 15925248               wsum8 @ 15958016
//  Kb (bf16) @ byte 63897600      Vt (bf16) @ byte 80674816
#define NOFF2 8388608
#define NOFF4 12582912
#define NOFF8 14680064
#define WOFF1 15728640
#define WOFF2 15859712
#define WOFF4 15925248
#define WOFF8 15958016

// ---------------------------------------------------------------------------
// Pre-pass: Kb = bf16(K) same layout; Vt[d] = bf16(V) transposed per dilation:
// Vt[d][bh][dim][jd] = V[bh][jd*d][dim].
// ---------------------------------------------------------------------------
__global__ __launch_bounds__(256)
void prep_kernel(const float* __restrict__ K, const float* __restrict__ V,
                 u16* __restrict__ Kb, u16* __restrict__ Vt)
{
    __shared__ __align__(16) char tl[64 * 128];   // [64 key][64 dim] bf16, swizzled
    int blk = blockIdx.x;
    const int t = threadIdx.x;

    if (blk < 2048) {                              // ---- K convert ----
        const int bh = blk >> 6, qt = blk & 63;
        const int q = qt * 64 + (t >> 2), dd0 = (t & 3) * 16;
        const float* kp = K + ((size_t)bh * 4096 + q) * 64 + dd0;
        float4 x0 = ((const float4*)kp)[0], x1 = ((const float4*)kp)[1];
        float4 x2 = ((const float4*)kp)[2], x3 = ((const float4*)kp)[3];
        F8 f0, f1;
        f0.u[0] = pk2(x0.x, x0.y); f0.u[1] = pk2(x0.z, x0.w);
        f0.u[2] = pk2(x1.x, x1.y); f0.u[3] = pk2(x1.z, x1.w);
        f1.u[0] = pk2(x2.x, x2.y); f1.u[1] = pk2(x2.z, x2.w);
        f1.u[2] = pk2(x3.x, x3.y); f1.u[3] = pk2(x3.z, x3.w);
        u16* op = Kb + ((size_t)bh * 4096 + q) * 64 + dd0;
        ((uint4*)op)[0] = f0.q; ((uint4*)op)[1] = f1.q;
        return;
    }
    blk -= 2048;                                   // ---- V transpose ----
    int d, Ld; size_t vtoff;
    if (blk < 2048)      { d = 1; Ld = 4096; vtoff = 0; }
    else if (blk < 3072) { blk -= 2048; d = 2; Ld = 2048; vtoff = 8388608; }
    else if (blk < 3584) { blk -= 3072; d = 4; Ld = 1024; vtoff = 12582912; }
    else                 { blk -= 3584; d = 8; Ld = 512;  vtoff = 14680064; }
    const int tpb = Ld >> 6;
    const int bh = blk / tpb, jt = blk % tpb;
    {   // load 64 (dilated) rows x 64 dims, cvt, swizzled LDS
        const int j = t >> 2, dd0 = (t & 3) * 16;
        const int q = (jt * 64 + j) * d;
        const float* vp = V + ((size_t)bh * 4096 + q) * 64 + dd0;
        float4 x0 = ((const float4*)vp)[0], x1 = ((const float4*)vp)[1];
        float4 x2 = ((const float4*)vp)[2], x3 = ((const float4*)vp)[3];
        F8 f0, f1;
        f0.u[0] = pk2(x0.x, x0.y); f0.u[1] = pk2(x0.z, x0.w);
        f0.u[2] = pk2(x1.x, x1.y); f0.u[3] = pk2(x1.z, x1.w);
        f1.u[0] = pk2(x2.x, x2.y); f1.u[1] = pk2(x2.z, x2.w);
        f1.u[2] = pk2(x3.x, x3.y); f1.u[3] = pk2(x3.z, x3.w);
        *(uint4*)(tl + SWZ(j * 128 + dd0 * 2, j)) = f0.q;
        *(uint4*)(tl + SWZ(j * 128 + dd0 * 2 + 16, j)) = f1.q;
    }
    __syncthreads();
    {   // store transposed: row = dim, 16 keys per thread
        const int dd = t >> 2, jb = (t & 3) * 16;
        F8 f0, f1;
#pragma unroll
        for (int i = 0; i < 8; ++i) {
            f0.s[i] = *(const u16*)(tl + SWZ((jb + i) * 128 + dd * 2, jb + i));
            f1.s[i] = *(const u16*)(tl + SWZ((jb + 8 + i) * 128 + dd * 2, jb + 8 + i));
        }
        u16* op = Vt + vtoff + ((size_t)bh * 64 + dd) * Ld + jt * 64 + jb;
        ((uint4*)op)[0] = f0.q; ((uint4*)op)[1] = f1.q;
    }
}

// ---------------------------------------------------------------------------
// Fused flash attention — round-13/17 structure (fastest measured: 134.6us).
// All dilations in ONE 1920-block launch; each dilation writes its PRIVATE
// num/wsum slice with plain stores (no atomics, no memset). Round-6 inner
// loop: 256 thr = 4 waves, 32 q-rows/wave, swapped QK^T, no online max (ref
// computes unmaxed exp; scores ~N(0,1)), P via LDS, 1-deep prefetch.
// ---------------------------------------------------------------------------
__global__ __launch_bounds__(256)
void attn_fused(const float* __restrict__ Q, const u16* __restrict__ Kb,
                const u16* __restrict__ Vt, float* __restrict__ ws)
{
    const int L = 4096;
    const int per = gridDim.x >> 3;                // bijective XCD swizzle
    const int wg0 = blockIdx.x;
    const int wg = (wg0 & 7) * per + (wg0 >> 3);

    int d, npb, bs, rel; size_t vtoff, noff, woff;
    if (wg < 1024)      { d = 1; npb = 32; bs = 1024; rel = wg;
                          vtoff = 0;        noff = 0;     woff = WOFF1; }
    else if (wg < 1536) { d = 2; npb = 16; bs = 1024; rel = wg - 1024;
                          vtoff = 8388608;  noff = NOFF2; woff = WOFF2; }
    else if (wg < 1792) { d = 4; npb = 8;  bs = 1024; rel = wg - 1536;
                          vtoff = 12582912; noff = NOFF4; woff = WOFF4; }
    else                { d = 8; npb = 4;  bs = 512;  rel = wg - 1792;
                          vtoff = 14680064; noff = NOFF8; woff = WOFF8; }

    const int bh = rel / npb;
    const int qt = rel % npb;
    const int b = bh >> 3, h = bh & 7;
    const int tid = threadIdx.x;
    const int w = tid >> 6, lane = tid & 63;
    const int g = lane >> 4, c = lane & 15;
    const int bstart = ((qt * 128) / bs) * bs;
    const int qrow0 = qt * 128 + w * 32;
    const int Ldq = npb * 128;
    const int nt = bs >> 6;

    __shared__ __align__(16) char smem[32 * 1024];
    char* const Kls = smem;
    char* const Vls = smem + 8192;
    char* const Pls = smem + 16384 + w * 4096;

    const size_t base = (size_t)bh * L * 64;
    const size_t vbase = vtoff + (size_t)bh * 64 * Ldq;
    const float qs = 0.125f * 1.44269504088896341f;

    bf16x8 qf[2][2];
#pragma unroll
    for (int qi = 0; qi < 2; ++qi) {
        const float* qp = Q + base + (size_t)(qrow0 + qi * 16 + c) * d * 64 + g * 8;
#pragma unroll
        for (int s2 = 0; s2 < 2; ++s2) {
            float4 x = ((const float4*)(qp + s2 * 32))[0];
            float4 y = ((const float4*)(qp + s2 * 32))[1];
            F8 f;
            f.u[0] = pk2(x.x * qs, x.y * qs);
            f.u[1] = pk2(x.z * qs, x.w * qs);
            f.u[2] = pk2(y.x * qs, y.y * qs);
            f.u[3] = pk2(y.z * qs, y.w * qs);
            qf[qi][s2] = f.v;
        }
    }

    f32x4 o[2][4];
#pragma unroll
    for (int qi = 0; qi < 2; ++qi)
#pragma unroll
        for (int dj = 0; dj < 4; ++dj) o[qi][dj] = (f32x4){0.f, 0.f, 0.f, 0.f};
    float lrow[2] = {0.f, 0.f};

    const int krow = tid >> 2, kc = tid & 3;

    uint4 ka, kb2, va, vb;
    const u16* kp0 = Kb + base + (size_t)(bstart + krow) * d * 64 + kc * 16;
    const u16* vp0 = Vt + vbase + (size_t)lane * Ldq + bstart + w * 16;
    const size_t kstep = (size_t)64 * d * 64;
    ka = ((const uint4*)kp0)[0]; kb2 = ((const uint4*)kp0)[1];
    va = ((const uint4*)vp0)[0]; vb = ((const uint4*)vp0)[1];

    for (int t = 0; t < nt; ++t) {
        *(uint4*)(Kls + SWZ(krow * 128 + kc * 32, krow)) = ka;
        *(uint4*)(Kls + SWZ(krow * 128 + kc * 32 + 16, krow)) = kb2;
        *(uint4*)(Vls + SWZ(lane * 128 + w * 32, lane)) = va;
        *(uint4*)(Vls + SWZ(lane * 128 + w * 32 + 16, lane)) = vb;
        __syncthreads();

        if (t + 1 < nt) {
            const u16* kp = kp0 + (size_t)(t + 1) * kstep;
            const u16* vp = vp0 + (t + 1) * 64;
            ka = ((const uint4*)kp)[0]; kb2 = ((const uint4*)kp)[1];
            va = ((const uint4*)vp)[0]; vb = ((const uint4*)vp)[1];
        }

        f32x4 st[2][4];
#pragma unroll
        for (int kj = 0; kj < 4; ++kj) {
            const int row = 16 * kj + c;
            bf16x8 kf0 = *(const bf16x8*)(Kls + SWZ(row * 128 + g * 16, row));
            bf16x8 kf1 = *(const bf16x8*)(Kls + SWZ(row * 128 + 64 + g * 16, row));
            f32x4 z = (f32x4){0.f, 0.f, 0.f, 0.f};
            st[0][kj] = MFMA(kf1, qf[0][1], MFMA(kf0, qf[0][0], z));
            st[1][kj] = MFMA(kf1, qf[1][1], MFMA(kf0, qf[1][0], z));
        }

#pragma unroll
        for (int qi = 0; qi < 2; ++qi) {
            const int prow = 16 * qi + c;
            float rs = 0.f;
#pragma unroll
            for (int kj = 0; kj < 4; ++kj) {
                const float p0 = exp2f(st[qi][kj][0]);
                const float p1 = exp2f(st[qi][kj][1]);
                const float p2 = exp2f(st[qi][kj][2]);
                const float p3 = exp2f(st[qi][kj][3]);
                rs += (p0 + p1) + (p2 + p3);
                uint2 pv; pv.x = pk2(p0, p1); pv.y = pk2(p2, p3);
                *(uint2*)(Pls + SWZ(prow * 128 + kj * 32 + g * 8, prow)) = pv;
            }
            lrow[qi] += rs;
        }

#pragma unroll
        for (int s = 0; s < 2; ++s) {
            bf16x8 vf[4], pf[2];
#pragma unroll
            for (int dj = 0; dj < 4; ++dj) {
                const int row = 16 * dj + c;
                vf[dj] = *(const bf16x8*)(Vls + SWZ(row * 128 + s * 64 + g * 16, row));
            }
#pragma unroll
            for (int qi = 0; qi < 2; ++qi) {
                const int row = 16 * qi + c;
                pf[qi] = *(const bf16x8*)(Pls + SWZ(row * 128 + s * 64 + g * 16, row));
            }
#pragma unroll
            for (int qi = 0; qi < 2; ++qi)
#pragma unroll
                for (int dj = 0; dj < 4; ++dj)
                    o[qi][dj] = MFMA(pf[qi], vf[dj], o[qi][dj]);
        }
        __syncthreads();
    }

    // ---- epilogue: plain stores into this dilation's private slice ----
#pragma unroll
    for (int qi = 0; qi < 2; ++qi) {
        float lq = lrow[qi];
        lq += __shfl_xor(lq, 16);
        lq += __shfl_xor(lq, 32);
#pragma unroll
        for (int r = 0; r < 4; ++r) {
            const int q = qrow0 + 16 * qi + 4 * g + r;
            float* np = ws + noff + ((size_t)b * Ldq + q) * 512 + h * 64 + c;
#pragma unroll
            for (int dj = 0; dj < 4; ++dj) np[dj * 16] = o[qi][dj][r];
        }
        if (g == 0) {
            const int q2 = qrow0 + 16 * qi + c;
            ws[woff + ((size_t)b * Ldq + q2) * 8 + h] = lq;
        }
    }
}

// ---------------------------------------------------------------------------
// Merge: fold num2/4/8 (and wsum2/4/8) into slice 1. Row-owned: each even
// row li=2j handled by one 128-lane half-block; branches (li%4, li%8) are
// uniform per half-block -> no divergence penalty, no races, no atomics.
// ---------------------------------------------------------------------------
__global__ __launch_bounds__(256)
void merge_kernel(float* __restrict__ ws)
{
    const int tid = threadIdx.x;
    const int er = blockIdx.x * 2 + (tid >> 7);    // even-row index 0..8191
    const int lane = tid & 127;
    const int b = er >> 11;                        // batch
    const int j = er & 2047;                       // li = 2j
    const int li = 2 * j;

    float4* dst = (float4*)(ws + ((size_t)b * 4096 + li) * 512) + lane;
    float4 a = *dst;
    const float4 x2 = *((const float4*)(ws + NOFF2 + ((size_t)b * 2048 + j) * 512) + lane);
    a.x += x2.x; a.y += x2.y; a.z += x2.z; a.w += x2.w;
    if ((li & 3) == 0) {
        const float4 x4 = *((const float4*)(ws + NOFF4 + ((size_t)b * 1024 + (li >> 2)) * 512) + lane);
        a.x += x4.x; a.y += x4.y; a.z += x4.z; a.w += x4.w;
    }
    if ((li & 7) == 0) {
        const float4 x8 = *((const float4*)(ws + NOFF8 + ((size_t)b * 512 + (li >> 3)) * 512) + lane);
        a.x += x8.x; a.y += x8.y; a.z += x8.z; a.w += x8.w;
    }
    *dst = a;

    if (lane < 8) {
        const int h = lane;
        float add = ws[WOFF2 + ((size_t)b * 2048 + j) * 8 + h];
        if ((li & 3) == 0) add += ws[WOFF4 + ((size_t)b * 1024 + (li >> 2)) * 8 + h];
        if ((li & 7) == 0) add += ws[WOFF8 + ((size_t)b * 512 + (li >> 3)) * 8 + h];
        ws[WOFF1 + ((size_t)b * 4096 + li) * 8 + h] += add;
    }
}

// ---------------------------------------------------------------------------
// out(16384,512) = [num/wsum] @ Wo^T + bo.  128x128 tile, BK=64, 4 waves.
// Split-precision bf16 (hi+lo): 3 MFMAs per product. XCD swizzle for A reuse.
// ---------------------------------------------------------------------------
__global__ __launch_bounds__(256)
void proj_mfma(const float* __restrict__ num, const float* __restrict__ wsum,
               const float* __restrict__ Wo, const float* __restrict__ bo,
               float* __restrict__ out)
{
    __shared__ __align__(16) char smem[64 * 1024];
    char* const Ah = smem;
    char* const Al = smem + 16384;
    char* const Bh = smem + 32768;
    char* const Bl = smem + 49152;

    const int tid = threadIdx.x;
    const int w = tid >> 6, lane = tid & 63, g = lane >> 4, c = lane & 15;
    const int wm = (w >> 1) * 64, wn = (w & 1) * 64;
    const int per = gridDim.x >> 3;
    const int wg0 = blockIdx.x;
    const int wg = (wg0 & 7) * per + (wg0 >> 3);
    const int bm = (wg >> 2) * 128, bn = (wg & 3) * 128;
    const int srow = tid >> 1, koff = (tid & 1) * 32;

    f32x4 acc[4][4];
#pragma unroll
    for (int mi = 0; mi < 4; ++mi)
#pragma unroll
        for (int ni = 0; ni < 4; ++ni) acc[mi][ni] = (f32x4){0.f, 0.f, 0.f, 0.f};

    for (int bk = 0; bk < 512; bk += 64) {
        {
            const float* ap = num + (size_t)(bm + srow) * 512 + bk + koff;
            const float winv = 1.0f / wsum[(size_t)(bm + srow) * 8 + (bk >> 6)];
#pragma unroll
            for (int i = 0; i < 8; ++i) {
                float4 a4 = ((const float4*)ap)[i];
                float v0 = a4.x * winv, v1 = a4.y * winv, v2 = a4.z * winv, v3 = a4.w * winv;
                u16 h0 = f2bf(v0), h1 = f2bf(v1), h2 = f2bf(v2), h3 = f2bf(v3);
                uint2 hiw; hiw.x = h0 | ((unsigned)h1 << 16); hiw.y = h2 | ((unsigned)h3 << 16);
                uint2 lo;
                lo.x = f2bf(v0 - bf2f(h0)) | ((unsigned)f2bf(v1 - bf2f(h1)) << 16);
                lo.y = f2bf(v2 - bf2f(h2)) | ((unsigned)f2bf(v3 - bf2f(h3)) << 16);
                const int off = SWZ(srow * 128 + koff * 2 + i * 8, srow);
                *(uint2*)(Ah + off) = hiw;
                *(uint2*)(Al + off) = lo;
            }
            const float* bp = Wo + (size_t)(bn + srow) * 512 + bk + koff;
#pragma unroll
            for (int i = 0; i < 8; ++i) {
                float4 a4 = ((const float4*)bp)[i];
                u16 h0 = f2bf(a4.x), h1 = f2bf(a4.y), h2 = f2bf(a4.z), h3 = f2bf(a4.w);
                uint2 hiw; hiw.x = h0 | ((unsigned)h1 << 16); hiw.y = h2 | ((unsigned)h3 << 16);
                uint2 lo;
                lo.x = f2bf(a4.x - bf2f(h0)) | ((unsigned)f2bf(a4.y - bf2f(h1)) << 16);
                lo.y = f2bf(a4.z - bf2f(h2)) | ((unsigned)f2bf(a4.w - bf2f(h3)) << 16);
                const int off = SWZ(srow * 128 + koff * 2 + i * 8, srow);
                *(uint2*)(Bh + off) = hiw;
                *(uint2*)(Bl + off) = lo;
            }
        }
        __syncthreads();
#pragma unroll
        for (int s = 0; s < 2; ++s) {
            bf16x8 ah[4], al[4], bh[4], bl[4];
#pragma unroll
            for (int mi = 0; mi < 4; ++mi) {
                const int row = wm + 16 * mi + c;
                const int off = SWZ(row * 128 + s * 64 + g * 16, row);
                ah[mi] = *(const bf16x8*)(Ah + off);
                al[mi] = *(const bf16x8*)(Al + off);
            }
#pragma unroll
            for (int ni = 0; ni < 4; ++ni) {
                const int row = wn + 16 * ni + c;
                const int off = SWZ(row * 128 + s * 64 + g * 16, row);
                bh[ni] = *(const bf16x8*)(Bh + off);
                bl[ni] = *(const bf16x8*)(Bl + off);
            }
#pragma unroll
            for (int mi = 0; mi < 4; ++mi)
#pragma unroll
                for (int ni = 0; ni < 4; ++ni) {
                    acc[mi][ni] = MFMA(ah[mi], bh[ni], acc[mi][ni]);
                    acc[mi][ni] = MFMA(ah[mi], bl[ni], acc[mi][ni]);
                    acc[mi][ni] = MFMA(al[mi], bh[ni], acc[mi][ni]);
                }
        }
        __syncthreads();
    }

    float bias[4];
#pragma unroll
    for (int ni = 0; ni < 4; ++ni) bias[ni] = bo[bn + wn + 16 * ni + c];
#pragma unroll
    for (int mi = 0; mi < 4; ++mi)
#pragma unroll
        for (int r = 0; r < 4; ++r) {
            float* op = out + (size_t)(bm + wm + 16 * mi + 4 * g + r) * 512 + bn + wn + c;
#pragma unroll
            for (int ni = 0; ni < 4; ++ni)
                op[ni * 16] = acc[mi][ni][r] + bias[ni];
        }
}

extern "C" void kernel_launch(void* const* d_in, const int* in_sizes, int n_in,
                              void* d_out, int out_size, void* d_ws, size_t ws_size,
                              hipStream_t stream)
{
    const float* Q  = (const float*)d_in[0];
    const float* K  = (const float*)d_in[1];
    const float* V  = (const float*)d_in[2];
    const float* Wo = (const float*)d_in[3];
    const float* bo = (const float*)d_in[4];
    float* out = (float*)d_out;

    float* ws = (float*)d_ws;
    u16* Kb = (u16*)((char*)d_ws + 63897600);     // 16.78 MB
    u16* Vt = (u16*)((char*)d_ws + 80674816);     // 31.46 MB (ends ~112.1 MB)

    hipLaunchKernelGGL(prep_kernel, dim3(5888), dim3(256), 0, stream, K, V, Kb, Vt);
    hipLaunchKernelGGL(attn_fused, dim3(1920), dim3(256), 0, stream, Q, Kb, Vt, ws);
    hipLaunchKernelGGL(merge_kernel, dim3(4096), dim3(256), 0, stream, ws);
    hipLaunchKernelGGL(proj_mfma, dim3(512), dim3(256), 0, stream,
                       ws, ws + WOFF1, Wo, bo, out);
}